// Round 9
// baseline (187.236 us; speedup 1.0000x reference)
//
#include <hip/hip_runtime.h>
#include <hip/hip_bf16.h>

#define S_LEN 2048
#define NH 16
#define DH 64
#define DMODEL 1024
#define M_TOT 4096
#define LOG2E 1.44269504f

typedef __attribute__((ext_vector_type(8))) short bf16x8;
typedef __attribute__((ext_vector_type(4))) float f32x4;
typedef unsigned short u16;
typedef unsigned short us8 __attribute__((ext_vector_type(8)));

__device__ inline u16 f2bf(float f) {
    union { float f; unsigned u; } c; c.f = f;
    unsigned r = c.u + 0x7fffu + ((c.u >> 16) & 1u);
    return (u16)(r >> 16);
}

__device__ inline void load_lds16(const u16* g, u16* l) {
    __builtin_amdgcn_global_load_lds((const __attribute__((address_space(1))) void*)g,
                                     (__attribute__((address_space(3))) void*)l, 16, 0, 0);
}

__device__ inline us8 pack8(float4 a, float4 b) {
    us8 o;
    o[0] = f2bf(a.x); o[1] = f2bf(a.y); o[2] = f2bf(a.z); o[3] = f2bf(a.w);
    o[4] = f2bf(b.x); o[5] = f2bf(b.y); o[6] = f2bf(b.z); o[7] = f2bf(b.w);
    return o;
}

struct W4 { float4 a, b, c, d; };
__device__ inline W4 wload(const float* p) {
    W4 r;
    r.a = *(const float4*)(p);
    r.b = *(const float4*)(p + 4);
    r.c = *(const float4*)(p + 8);
    r.d = *(const float4*)(p + 12);
    return r;
}

// ---------------------------------------------------------------------------
// fp32 -> bf16 (RNE), grid*2048 elements
// ---------------------------------------------------------------------------
__global__ __launch_bounds__(256) void conv_bf16(
    const float* __restrict__ src, u16* __restrict__ dst)
{
    const size_t i = ((size_t)blockIdx.x * 256 + threadIdx.x) * 8;
    const float4 a = *(const float4*)(src + i);
    const float4 b = *(const float4*)(src + i + 4);
    *(us8*)(dst + i) = pack8(a, b);
}

// ---------------------------------------------------------------------------
// cm[b,s] = e^{mask[b,s]} (f32 + bf16). B*S = 4096 elements.
// ---------------------------------------------------------------------------
__global__ __launch_bounds__(256) void gen_cm(
    const float* __restrict__ mask, float* __restrict__ cm, u16* __restrict__ cmb)
{
    const int i = blockIdx.x * 256 + threadIdx.x;
    const float c = exp2f(mask[i] * LOG2E);
    cm[i] = c;
    cmb[i] = f2bf(c);
}

// ---------------------------------------------------------------------------
// QKV GEMM, 3-stage A pipeline (DMA 2 tiles ahead) + counted vmcnt barrier.
// W fp32 reg-prefetched (double reg-set) -> convert -> ds_write (dbuf).
// z=0: Q flat scaled by 0.125*log2e; z=1: K flat; z=2: V*cm -> vT (B,H,DH,S)
// ---------------------------------------------------------------------------
__global__ __launch_bounds__(256) void gemm_qkv(
    const u16* __restrict__ hsb,
    const float* __restrict__ Wq, const float* __restrict__ Wk, const float* __restrict__ Wv,
    const float* __restrict__ bq, const float* __restrict__ bk, const float* __restrict__ bv,
    const float* __restrict__ cm,
    u16* __restrict__ qb, u16* __restrict__ kb, u16* __restrict__ vT)
{
    __shared__ u16 lA[3][128 * 32];
    __shared__ u16 lB[2][128 * 32];
    const int tid = threadIdx.x, lane = tid & 63, w = tid >> 6;
    const int l15 = lane & 15, lg = lane >> 4;
    const int wr = w >> 1, wc = w & 1;
    const int m0 = blockIdx.y * 128, n0 = blockIdx.x * 128;
    const int z = blockIdx.z;
    const float* W = (z == 0) ? Wq : (z == 1) ? Wk : Wv;
    const float* bias = (z == 0) ? bq : (z == 1) ? bk : bv;

    const u16* aptr[2]; int adst[2];
#pragma unroll
    for (int i = 0; i < 2; ++i) {
        const int rowb = (w * 2 + i) * 16;
        const int row = rowb + (lane >> 2);
        const int gc = (lane & 3) ^ ((row >> 1) & 3);
        aptr[i] = hsb + (size_t)(m0 + row) * DMODEL + gc * 8;
        adst[i] = rowb * 32;
    }
    const int wrow = tid >> 1, wch = tid & 1;
    const float* wp = W + (size_t)(n0 + wrow) * DMODEL + wch * 16;
    const int wsw = (wrow >> 1) & 3;
    const int bo0 = wrow * 32 + ((wch * 2) ^ wsw) * 8;
    const int bo1 = wrow * 32 + ((wch * 2 + 1) ^ wsw) * 8;
    int afo[4], bfo[4];
#pragma unroll
    for (int i = 0; i < 4; ++i) {
        const int rA = wr * 64 + i * 16 + l15;
        afo[i] = rA * 32 + ((lg ^ ((rA >> 1) & 3)) * 8);
        const int rB = wc * 64 + i * 16 + l15;
        bfo[i] = rB * 32 + ((lg ^ ((rB >> 1) & 3)) * 8);
    }

    f32x4 acc[4][4] = {};

    // prologue: W(0) regs first (so its wait doesn't drain DMA), A0,A1 DMA,
    // write lB[0], load W(1)
    W4 wcur = wload(wp);
    load_lds16(aptr[0], &lA[0][adst[0]]);
    load_lds16(aptr[1], &lA[0][adst[1]]);
    load_lds16(aptr[0] + 32, &lA[1][adst[0]]);
    load_lds16(aptr[1] + 32, &lA[1][adst[1]]);
    *(us8*)&lB[0][bo0] = pack8(wcur.a, wcur.b);
    *(us8*)&lB[0][bo1] = pack8(wcur.c, wcur.d);
    W4 wnxt = wload(wp + 32);
    __syncthreads();

    int ia = 0, ib = 1, ic = 2;
    auto ITER = [&](int t, int ia2, int ic2, int rdB, W4& wWr, W4& wLd) {
        if (t + 2 < 32) {
            load_lds16(aptr[0] + (t + 2) * 32, &lA[ic2][adst[0]]);
            load_lds16(aptr[1] + (t + 2) * 32, &lA[ic2][adst[1]]);
            wLd = wload(wp + (t + 2) * 32);
        }
        bf16x8 af[4], bfr[4];
#pragma unroll
        for (int i = 0; i < 4; ++i) {
            af[i] = *(bf16x8*)&lA[ia2][afo[i]];
            bfr[i] = *(bf16x8*)&lB[rdB][bfo[i]];
        }
        __builtin_amdgcn_s_setprio(1);
#pragma unroll
        for (int i = 0; i < 4; ++i)
#pragma unroll
            for (int j = 0; j < 4; ++j)
                acc[i][j] = __builtin_amdgcn_mfma_f32_16x16x32_bf16(af[i], bfr[j], acc[i][j], 0, 0, 0);
        __builtin_amdgcn_s_setprio(0);
        if (t + 1 < 32) {
            *(us8*)&lB[rdB ^ 1][bo0] = pack8(wWr.a, wWr.b);
            *(us8*)&lB[rdB ^ 1][bo1] = pack8(wWr.c, wWr.d);
        }
        if (t < 31) {
            asm volatile("s_waitcnt vmcnt(6) lgkmcnt(0)" ::: "memory");
            __builtin_amdgcn_s_barrier();
        }
    };

    for (int t = 0; t < 32; t += 2) {
        ITER(t, ia, ic, 0, wnxt, wcur);
        int tmp = ia; ia = ib; ib = ic; ic = tmp;
        ITER(t + 1, ia, ic, 1, wcur, wnxt);
        tmp = ia; ia = ib; ib = ic; ic = tmp;
    }

    const float qsc = 0.125f * LOG2E;
    float bn[4];
#pragma unroll
    for (int j = 0; j < 4; ++j) bn[j] = bias[n0 + wc * 64 + j * 16 + l15];

#pragma unroll
    for (int i = 0; i < 4; ++i) {
        const int mbase = m0 + wr * 64 + i * 16 + lg * 4;
        if (z == 0) {
#pragma unroll
            for (int j = 0; j < 4; ++j) {
                const int n = n0 + wc * 64 + j * 16 + l15;
#pragma unroll
                for (int e = 0; e < 4; ++e)
                    qb[(size_t)(mbase + e) * DMODEL + n] = f2bf((acc[i][j][e] + bn[j]) * qsc);
            }
        } else if (z == 1) {
#pragma unroll
            for (int j = 0; j < 4; ++j) {
                const int n = n0 + wc * 64 + j * 16 + l15;
#pragma unroll
                for (int e = 0; e < 4; ++e)
                    kb[(size_t)(mbase + e) * DMODEL + n] = f2bf(acc[i][j][e] + bn[j]);
            }
        } else {
            const int bb = mbase >> 11, s = mbase & 2047;
            const float4 c4 = *(const float4*)&cm[bb * S_LEN + s];
#pragma unroll
            for (int j = 0; j < 4; ++j) {
                const int n = n0 + wc * 64 + j * 16 + l15;
                const int hh = n >> 6, dh = n & 63;
                ushort4 uv;
                uv.x = f2bf((acc[i][j][0] + bn[j]) * c4.x);
                uv.y = f2bf((acc[i][j][1] + bn[j]) * c4.y);
                uv.z = f2bf((acc[i][j][2] + bn[j]) * c4.z);
                uv.w = f2bf((acc[i][j][3] + bn[j]) * c4.w);
                *(ushort4*)&vT[((size_t)(bb * NH + hh) * DH + dh) * S_LEN + s] = uv;
            }
        }
    }
}

// ---------------------------------------------------------------------------
// O-projection, same 3-stage pipeline; A=ctx bf16 DMA, W=Wo fp32 reg-staged
// ---------------------------------------------------------------------------
__global__ __launch_bounds__(256) void gemm_o(
    const u16* __restrict__ ctx, const float* __restrict__ Wo,
    const float* __restrict__ bo, const float* __restrict__ resid,
    float* __restrict__ out)
{
    __shared__ u16 lA[3][128 * 32];
    __shared__ u16 lB[2][128 * 32];
    const int tid = threadIdx.x, lane = tid & 63, w = tid >> 6;
    const int l15 = lane & 15, lg = lane >> 4;
    const int wr = w >> 1, wc = w & 1;
    const int m0 = blockIdx.y * 128, n0 = blockIdx.x * 128;

    const u16* aptr[2]; int adst[2];
#pragma unroll
    for (int i = 0; i < 2; ++i) {
        const int rowb = (w * 2 + i) * 16;
        const int row = rowb + (lane >> 2);
        const int gc = (lane & 3) ^ ((row >> 1) & 3);
        aptr[i] = ctx + (size_t)(m0 + row) * DMODEL + gc * 8;
        adst[i] = rowb * 32;
    }
    const int wrow = tid >> 1, wch = tid & 1;
    const float* wp = Wo + (size_t)(n0 + wrow) * DMODEL + wch * 16;
    const int wsw = (wrow >> 1) & 3;
    const int bo0 = wrow * 32 + ((wch * 2) ^ wsw) * 8;
    const int bo1 = wrow * 32 + ((wch * 2 + 1) ^ wsw) * 8;
    int afo[4], bfo[4];
#pragma unroll
    for (int i = 0; i < 4; ++i) {
        const int rA = wr * 64 + i * 16 + l15;
        afo[i] = rA * 32 + ((lg ^ ((rA >> 1) & 3)) * 8);
        const int rB = wc * 64 + i * 16 + l15;
        bfo[i] = rB * 32 + ((lg ^ ((rB >> 1) & 3)) * 8);
    }

    f32x4 acc[4][4] = {};

    W4 wcur = wload(wp);
    load_lds16(aptr[0], &lA[0][adst[0]]);
    load_lds16(aptr[1], &lA[0][adst[1]]);
    load_lds16(aptr[0] + 32, &lA[1][adst[0]]);
    load_lds16(aptr[1] + 32, &lA[1][adst[1]]);
    *(us8*)&lB[0][bo0] = pack8(wcur.a, wcur.b);
    *(us8*)&lB[0][bo1] = pack8(wcur.c, wcur.d);
    W4 wnxt = wload(wp + 32);
    __syncthreads();

    int ia = 0, ib = 1, ic = 2;
    auto ITER = [&](int t, int ia2, int ic2, int rdB, W4& wWr, W4& wLd) {
        if (t + 2 < 32) {
            load_lds16(aptr[0] + (t + 2) * 32, &lA[ic2][adst[0]]);
            load_lds16(aptr[1] + (t + 2) * 32, &lA[ic2][adst[1]]);
            wLd = wload(wp + (t + 2) * 32);
        }
        bf16x8 af[4], bfr[4];
#pragma unroll
        for (int i = 0; i < 4; ++i) {
            af[i] = *(bf16x8*)&lA[ia2][afo[i]];
            bfr[i] = *(bf16x8*)&lB[rdB][bfo[i]];
        }
        __builtin_amdgcn_s_setprio(1);
#pragma unroll
        for (int i = 0; i < 4; ++i)
#pragma unroll
            for (int j = 0; j < 4; ++j)
                acc[i][j] = __builtin_amdgcn_mfma_f32_16x16x32_bf16(af[i], bfr[j], acc[i][j], 0, 0, 0);
        __builtin_amdgcn_s_setprio(0);
        if (t + 1 < 32) {
            *(us8*)&lB[rdB ^ 1][bo0] = pack8(wWr.a, wWr.b);
            *(us8*)&lB[rdB ^ 1][bo1] = pack8(wWr.c, wWr.d);
        }
        if (t < 31) {
            asm volatile("s_waitcnt vmcnt(6) lgkmcnt(0)" ::: "memory");
            __builtin_amdgcn_s_barrier();
        }
    };

    for (int t = 0; t < 32; t += 2) {
        ITER(t, ia, ic, 0, wnxt, wcur);
        int tmp = ia; ia = ib; ib = ic; ic = tmp;
        ITER(t + 1, ia, ic, 1, wcur, wnxt);
        tmp = ia; ia = ib; ib = ic; ic = tmp;
    }

#pragma unroll
    for (int i = 0; i < 4; ++i) {
#pragma unroll
        for (int j = 0; j < 4; ++j) {
            const int n = n0 + wc * 64 + j * 16 + l15;
            const float bnj = bo[n];
#pragma unroll
            for (int e = 0; e < 4; ++e) {
                const int m = m0 + wr * 64 + i * 16 + lg * 4 + e;
                out[(size_t)m * DMODEL + n] = acc[i][j][e] + bnj + resid[(size_t)m * DMODEL + n];
            }
        }
    }
}

// ---------------------------------------------------------------------------
// Flash attention, 8 waves x 16 q-rows (512 threads), KVBLK=128, counted
// vmcnt(8). Same LDS (80KB) but 2 blocks/CU now = 16 waves/CU.
// P = 2^(QK^T); mask folded into V-scale and cf; med_bias cancels.
// ---------------------------------------------------------------------------
__global__ __launch_bounds__(512, 4) void attn9(
    const u16* __restrict__ qg, const u16* __restrict__ kg,
    const u16* __restrict__ vTg, const u16* __restrict__ cmb,
    u16* __restrict__ ctx)
{
    __shared__ u16 Kl[2][128 * 64];   // [k-row][dh]  32 KB
    __shared__ u16 Vl[2][64 * 128];   // [dh][k]      32 KB
    __shared__ u16 Pl8[8][16 * 64];   // per-wave P   16 KB

    const int tid = threadIdx.x, lane = tid & 63, w = tid >> 6;  // w 0..7
    const int bx = blockIdx.x;
    const int x = bx & 7, rest = bx >> 3;
    const int qt = rest & 15, g2 = rest >> 4;
    const int hb = g2 * 8 + x;
    const int h = hb & (NH - 1), b = hb >> 4;

    const int l15 = lane & 15, lg = lane >> 4;
    const int q0 = qt * 128 + w * 16;
    const size_t rowbase = (size_t)b * S_LEN * DMODEL + h * DH;
    const size_t vbase = (size_t)(b * NH + h) * DH * S_LEN;
    u16* Pw = Pl8[w];

    // Q fragments (16 q-rows)
    bf16x8 aq[2];
#pragma unroll
    for (int kf = 0; kf < 2; ++kf)
        aq[kf] = *(const bf16x8*)&qg[rowbase + (size_t)(q0 + l15) * DMODEL + kf * 32 + lg * 8];

    // LDS read bases
    const int lx = l15 & 7;
    int kbase[2];                       // K frag / P frag (row stride 64)
#pragma unroll
    for (int kf = 0; kf < 2; ++kf)
        kbase[kf] = l15 * 64 + (((kf * 4 + lg) ^ lx) * 8);
    int vb2[4];                         // V frag (row stride 128)
#pragma unroll
    for (int kf2 = 0; kf2 < 4; ++kf2)
        vb2[kf2] = l15 * 128 + (((kf2 * 4 + lg) ^ lx) * 8);
    const int phi = l15 >> 3, plo = l15 & 7;

    // staging: 1024 16B-chunks each for K and V; 512 threads x 2 each
    size_t ksoff[2], vsoff[2];
    int ldst[2];
#pragma unroll
    for (int t = 0; t < 2; ++t) {
        const int ck = t * 512 + tid;
        const int krow = ck >> 3, kslot = ck & 7;
        ksoff[t] = (size_t)krow * DMODEL + ((kslot ^ (krow & 7)) * 8);
        const int vrow = ck >> 4, vslot = ck & 15;
        vsoff[t] = (size_t)vrow * S_LEN + ((vslot ^ (vrow & 7)) * 8);
        ldst[t] = (t * 512 + w * 64) * 8;
    }
    const u16* cmb_b = cmb + (size_t)b * S_LEN + lg * 8;

    f32x4 po[4] = {};
    f32x4 pol = {};

    // prologue: cf first, then DMA tile 0
    bf16x8 cf[4];
#pragma unroll
    for (int j = 0; j < 4; ++j)
        cf[j] = *(const bf16x8*)&cmb_b[j * 32];
    const u16* kp = kg + rowbase;
    const u16* vp = vTg + vbase;
#pragma unroll
    for (int t = 0; t < 2; ++t) {
        load_lds16(kp + ksoff[t], &Kl[0][ldst[t]]);
        load_lds16(vp + vsoff[t], &Vl[0][ldst[t]]);
    }
    kp += 128 * DMODEL; vp += 128;

    int cur = 0;
    for (int kt = 0; kt < S_LEN / 128; ++kt) {
        bf16x8 nx[4];
        if (kt + 1 < S_LEN / 128) {
#pragma unroll
            for (int j = 0; j < 4; ++j)
                nx[j] = *(const bf16x8*)&cmb_b[(kt + 1) * 128 + j * 32];
#pragma unroll
            for (int t = 0; t < 2; ++t) {
                load_lds16(kp + ksoff[t], &Kl[cur ^ 1][ldst[t]]);
                load_lds16(vp + vsoff[t], &Vl[cur ^ 1][ldst[t]]);
            }
            kp += 128 * DMODEL; vp += 128;
            asm volatile("s_waitcnt vmcnt(8)" ::: "memory");
        } else {
#pragma unroll
            for (int j = 0; j < 4; ++j) nx[j] = cf[j];
            asm volatile("s_waitcnt vmcnt(0)" ::: "memory");
        }
        __builtin_amdgcn_s_barrier();
        __builtin_amdgcn_sched_barrier(0);

#pragma unroll
        for (int h2 = 0; h2 < 2; ++h2) {
            // QK^T for this 64-k half: 8 MFMA
            f32x4 sa[4] = {};
            bf16x8 bkf[4][2];
#pragma unroll
            for (int nf = 0; nf < 4; ++nf)
#pragma unroll
                for (int kf = 0; kf < 2; ++kf)
                    bkf[nf][kf] = *(bf16x8*)&Kl[cur][(h2 * 4 + nf) * 1024 + kbase[kf]];
            __builtin_amdgcn_s_setprio(1);
#pragma unroll
            for (int nf = 0; nf < 4; ++nf)
#pragma unroll
                for (int kf = 0; kf < 2; ++kf)
                    sa[nf] = __builtin_amdgcn_mfma_f32_16x16x32_bf16(aq[kf], bkf[nf][kf], sa[nf], 0, 0, 0);
            __builtin_amdgcn_s_setprio(0);

            // softmax: p = 2^s -> bf16(trunc) -> wave-local P
#pragma unroll
            for (int e = 0; e < 4; ++e) {
                const int prow = lg * 4 + e;
                const int pbase = prow * 64 + plo;
                const int pxor = prow & 7;
#pragma unroll
                for (int nf = 0; nf < 4; ++nf) {
                    union { float f; unsigned u; } cv;
                    cv.f = exp2f(sa[nf][e]);
                    Pw[pbase + (((nf * 2 + phi) ^ pxor) * 8)] = (u16)(cv.u >> 16);
                }
            }

            // PV + c-weighted row-sum: 10 MFMA
#pragma unroll
            for (int j = 0; j < 2; ++j) {
                const int kf2 = h2 * 2 + j;
                bf16x8 ap = *(bf16x8*)&Pw[kbase[j]];
                bf16x8 bv[4];
#pragma unroll
                for (int df = 0; df < 4; ++df)
                    bv[df] = *(bf16x8*)&Vl[cur][df * 2048 + vb2[kf2]];
                const bf16x8 cfk = cf[kf2];
                __builtin_amdgcn_s_setprio(1);
#pragma unroll
                for (int df = 0; df < 4; ++df)
                    po[df] = __builtin_amdgcn_mfma_f32_16x16x32_bf16(ap, bv[df], po[df], 0, 0, 0);
                pol = __builtin_amdgcn_mfma_f32_16x16x32_bf16(ap, cfk, pol, 0, 0, 0);
                __builtin_amdgcn_s_setprio(0);
            }
        }
        __builtin_amdgcn_s_barrier();
#pragma unroll
        for (int j = 0; j < 4; ++j) cf[j] = nx[j];
        cur ^= 1;
    }

#pragma unroll
    for (int e = 0; e < 4; ++e) {
        const float inv = 1.0f / pol[e];
        const int qrow = q0 + lg * 4 + e;
#pragma unroll
        for (int df = 0; df < 4; ++df)
            ctx[((size_t)b * S_LEN + qrow) * DMODEL + h * DH + df * 16 + l15] = f2bf(po[df][e] * inv);
    }
}

// ---------------------------------------------------------------------------
// LayerNorm in-place, one row per block
// ---------------------------------------------------------------------------
__global__ __launch_bounds__(256) void ln_kernel(
    float* __restrict__ x, const float* __restrict__ gamma, const float* __restrict__ beta)
{
    const int row = blockIdx.x;
    const int tid = threadIdx.x;
    float4 vv = *(float4*)(x + (size_t)row * DMODEL + tid * 4);
    float s = vv.x + vv.y + vv.z + vv.w;
    float s2 = vv.x * vv.x + vv.y * vv.y + vv.z * vv.z + vv.w * vv.w;
#pragma unroll
    for (int d = 1; d < 64; d <<= 1) { s += __shfl_xor(s, d); s2 += __shfl_xor(s2, d); }
    __shared__ float rs[4], rs2[4];
    if ((tid & 63) == 0) { rs[tid >> 6] = s; rs2[tid >> 6] = s2; }
    __syncthreads();
    s = rs[0] + rs[1] + rs[2] + rs[3];
    s2 = rs2[0] + rs2[1] + rs2[2] + rs2[3];
    const float mu = s * (1.f / DMODEL);
    const float var = s2 * (1.f / DMODEL) - mu * mu;
    const float inv = rsqrtf(var + 1e-5f);
    const float4 g = *(const float4*)(gamma + tid * 4);
    const float4 bt = *(const float4*)(beta + tid * 4);
    vv.x = (vv.x - mu) * inv * g.x + bt.x;
    vv.y = (vv.y - mu) * inv * g.y + bt.y;
    vv.z = (vv.z - mu) * inv * g.z + bt.z;
    vv.w = (vv.w - mu) * inv * g.w + bt.w;
    *(float4*)(x + (size_t)row * DMODEL + tid * 4) = vv;
}

extern "C" void kernel_launch(void* const* d_in, const int* in_sizes, int n_in,
                              void* d_out, int out_size, void* d_ws, size_t ws_size,
                              hipStream_t stream) {
    const float* hs    = (const float*)d_in[0];
    const float* mask  = (const float*)d_in[1];
    const float* Wq    = (const float*)d_in[2];
    const float* bq    = (const float*)d_in[3];
    const float* Wk    = (const float*)d_in[4];
    const float* bk    = (const float*)d_in[5];
    const float* Wv    = (const float*)d_in[6];
    const float* bv    = (const float*)d_in[7];
    const float* Wo    = (const float*)d_in[9];
    const float* bo    = (const float*)d_in[10];
    const float* gamma = (const float*)d_in[11];
    const float* beta  = (const float*)d_in[12];
    float* out = (float*)d_out;

    const size_t MN = (size_t)M_TOT * DMODEL;     // 4M elements
    u16* qb      = (u16*)d_ws;          // [0, 8MB)
    u16* kb      = qb + MN;             // [8, 16MB)
    u16* vT      = kb + MN;             // [16, 24MB)
    u16* scratch = vT + MN;             // [24, 32MB): hsb, then ctx

    float* cm = out + MN - 4096 - 2048;
    u16*  cmb = (u16*)(out + MN - 2048);

    dim3 blk(256);

    conv_bf16<<<MN / 2048, blk, 0, stream>>>(hs, scratch);
    gen_cm<<<(2 * S_LEN) / 256, blk, 0, stream>>>(mask, cm, cmb);
    gemm_qkv<<<dim3(DMODEL / 128, M_TOT / 128, 3), blk, 0, stream>>>(
        scratch, Wq, Wk, Wv, bq, bk, bv, cm, qb, kb, vT);
    attn9<<<dim3(512), dim3(512), 0, stream>>>(qb, kb, vT, cmb, scratch);
    gemm_o<<<dim3(DMODEL / 128, M_TOT / 128), blk, 0, stream>>>(scratch, Wo, bo, hs, out);
    ln_kernel<<<M_TOT, blk, 0, stream>>>(out, gamma, beta);
}

// Round 10
// 168.656 us; speedup vs baseline: 1.1102x; 1.1102x over previous
//
#include <hip/hip_runtime.h>
#include <hip/hip_bf16.h>

#define S_LEN 2048
#define NH 16
#define DH 64
#define DMODEL 1024
#define M_TOT 4096
#define LOG2E 1.44269504f

typedef __attribute__((ext_vector_type(8))) short bf16x8;
typedef __attribute__((ext_vector_type(4))) float f32x4;
typedef unsigned short u16;
typedef unsigned short us8 __attribute__((ext_vector_type(8)));

__device__ inline u16 f2bf(float f) {
    union { float f; unsigned u; } c; c.f = f;
    unsigned r = c.u + 0x7fffu + ((c.u >> 16) & 1u);
    return (u16)(r >> 16);
}

__device__ inline void load_lds16(const u16* g, u16* l) {
    __builtin_amdgcn_global_load_lds((const __attribute__((address_space(1))) void*)g,
                                     (__attribute__((address_space(3))) void*)l, 16, 0, 0);
}

__device__ inline us8 pack8(float4 a, float4 b) {
    us8 o;
    o[0] = f2bf(a.x); o[1] = f2bf(a.y); o[2] = f2bf(a.z); o[3] = f2bf(a.w);
    o[4] = f2bf(b.x); o[5] = f2bf(b.y); o[6] = f2bf(b.z); o[7] = f2bf(b.w);
    return o;
}

// ---------------------------------------------------------------------------
// fp32 -> bf16 (RNE), grid*2048 elements
// ---------------------------------------------------------------------------
__global__ __launch_bounds__(256) void conv_bf16(
    const float* __restrict__ src, u16* __restrict__ dst)
{
    const size_t i = ((size_t)blockIdx.x * 256 + threadIdx.x) * 8;
    const float4 a = *(const float4*)(src + i);
    const float4 b = *(const float4*)(src + i + 4);
    *(us8*)(dst + i) = pack8(a, b);
}

// ---------------------------------------------------------------------------
// cm[b,s] = e^{mask[b,s]} (f32 + bf16). B*S = 4096 elements.
// ---------------------------------------------------------------------------
__global__ __launch_bounds__(256) void gen_cm(
    const float* __restrict__ mask, float* __restrict__ cm, u16* __restrict__ cmb)
{
    const int i = blockIdx.x * 256 + threadIdx.x;
    const float c = exp2f(mask[i] * LOG2E);
    cm[i] = c;
    cmb[i] = f2bf(c);
}

// ---------------------------------------------------------------------------
// QKV GEMM, 2-phase pipelined (r8-proven version)
// ---------------------------------------------------------------------------
__global__ __launch_bounds__(256) void gemm_qkv(
    const u16* __restrict__ hsb,
    const float* __restrict__ Wq, const float* __restrict__ Wk, const float* __restrict__ Wv,
    const float* __restrict__ bq, const float* __restrict__ bk, const float* __restrict__ bv,
    const float* __restrict__ cm,
    u16* __restrict__ qb, u16* __restrict__ kb, u16* __restrict__ vT)
{
    __shared__ u16 lA[2][128 * 32];
    __shared__ u16 lB[2][128 * 32];
    const int tid = threadIdx.x, lane = tid & 63, w = tid >> 6;
    const int l15 = lane & 15, lg = lane >> 4;
    const int wr = w >> 1, wc = w & 1;
    const int m0 = blockIdx.y * 128, n0 = blockIdx.x * 128;
    const int z = blockIdx.z;
    const float* W = (z == 0) ? Wq : (z == 1) ? Wk : Wv;
    const float* bias = (z == 0) ? bq : (z == 1) ? bk : bv;

    const u16* aptr[2]; int adst[2];
#pragma unroll
    for (int i = 0; i < 2; ++i) {
        const int rowb = (w * 2 + i) * 16;
        const int row = rowb + (lane >> 2);
        const int gc = (lane & 3) ^ ((row >> 1) & 3);
        aptr[i] = hsb + (size_t)(m0 + row) * DMODEL + gc * 8;
        adst[i] = rowb * 32;
    }
    const int wrow = tid >> 1, wch = tid & 1;
    const float* wp = W + (size_t)(n0 + wrow) * DMODEL + wch * 16;
    const int wsw = (wrow >> 1) & 3;
    const int bo0 = wrow * 32 + ((wch * 2) ^ wsw) * 8;
    const int bo1 = wrow * 32 + ((wch * 2 + 1) ^ wsw) * 8;
    int afo[4], bfo[4];
#pragma unroll
    for (int i = 0; i < 4; ++i) {
        const int rA = wr * 64 + i * 16 + l15;
        afo[i] = rA * 32 + ((lg ^ ((rA >> 1) & 3)) * 8);
        const int rB = wc * 64 + i * 16 + l15;
        bfo[i] = rB * 32 + ((lg ^ ((rB >> 1) & 3)) * 8);
    }

    f32x4 acc[4][4] = {};

    load_lds16(aptr[0], &lA[0][adst[0]]);
    load_lds16(aptr[1], &lA[0][adst[1]]);
    {
        const float4 w0 = *(const float4*)(wp);
        const float4 w1 = *(const float4*)(wp + 4);
        const float4 w2 = *(const float4*)(wp + 8);
        const float4 w3 = *(const float4*)(wp + 12);
        *(us8*)&lB[0][bo0] = pack8(w0, w1);
        *(us8*)&lB[0][bo1] = pack8(w2, w3);
    }
    __syncthreads();

    int cur = 0;
    for (int t = 0; t < 32; ++t) {
        float4 w0, w1, w2, w3;
        const bool notlast = (t < 31);
        if (notlast) {
            load_lds16(aptr[0] + (t + 1) * 32, &lA[cur ^ 1][adst[0]]);
            load_lds16(aptr[1] + (t + 1) * 32, &lA[cur ^ 1][adst[1]]);
            w0 = *(const float4*)(wp + (t + 1) * 32);
            w1 = *(const float4*)(wp + (t + 1) * 32 + 4);
            w2 = *(const float4*)(wp + (t + 1) * 32 + 8);
            w3 = *(const float4*)(wp + (t + 1) * 32 + 12);
        }
        bf16x8 af[4], bfr[4];
#pragma unroll
        for (int i = 0; i < 4; ++i) {
            af[i] = *(bf16x8*)&lA[cur][afo[i]];
            bfr[i] = *(bf16x8*)&lB[cur][bfo[i]];
        }
        __builtin_amdgcn_s_setprio(1);
#pragma unroll
        for (int i = 0; i < 4; ++i)
#pragma unroll
            for (int j = 0; j < 4; ++j)
                acc[i][j] = __builtin_amdgcn_mfma_f32_16x16x32_bf16(af[i], bfr[j], acc[i][j], 0, 0, 0);
        __builtin_amdgcn_s_setprio(0);
        if (notlast) {
            *(us8*)&lB[cur ^ 1][bo0] = pack8(w0, w1);
            *(us8*)&lB[cur ^ 1][bo1] = pack8(w2, w3);
            __syncthreads();
            cur ^= 1;
        }
    }

    const float qsc = 0.125f * LOG2E;
    float bn[4];
#pragma unroll
    for (int j = 0; j < 4; ++j) bn[j] = bias[n0 + wc * 64 + j * 16 + l15];

#pragma unroll
    for (int i = 0; i < 4; ++i) {
        const int mbase = m0 + wr * 64 + i * 16 + lg * 4;
        if (z == 0) {
#pragma unroll
            for (int j = 0; j < 4; ++j) {
                const int n = n0 + wc * 64 + j * 16 + l15;
#pragma unroll
                for (int e = 0; e < 4; ++e)
                    qb[(size_t)(mbase + e) * DMODEL + n] = f2bf((acc[i][j][e] + bn[j]) * qsc);
            }
        } else if (z == 1) {
#pragma unroll
            for (int j = 0; j < 4; ++j) {
                const int n = n0 + wc * 64 + j * 16 + l15;
#pragma unroll
                for (int e = 0; e < 4; ++e)
                    kb[(size_t)(mbase + e) * DMODEL + n] = f2bf(acc[i][j][e] + bn[j]);
            }
        } else {
            const int bb = mbase >> 11, s = mbase & 2047;
            const float4 c4 = *(const float4*)&cm[bb * S_LEN + s];
#pragma unroll
            for (int j = 0; j < 4; ++j) {
                const int n = n0 + wc * 64 + j * 16 + l15;
                const int hh = n >> 6, dh = n & 63;
                ushort4 uv;
                uv.x = f2bf((acc[i][j][0] + bn[j]) * c4.x);
                uv.y = f2bf((acc[i][j][1] + bn[j]) * c4.y);
                uv.z = f2bf((acc[i][j][2] + bn[j]) * c4.z);
                uv.w = f2bf((acc[i][j][3] + bn[j]) * c4.w);
                *(ushort4*)&vT[((size_t)(bb * NH + hh) * DH + dh) * S_LEN + s] = uv;
            }
        }
    }
}

// ---------------------------------------------------------------------------
// O-projection, 2-phase pipelined (r8-proven); A=ctx bf16 DMA, Wo fp32 staged
// ---------------------------------------------------------------------------
__global__ __launch_bounds__(256) void gemm_o(
    const u16* __restrict__ ctx, const float* __restrict__ Wo,
    const float* __restrict__ bo, const float* __restrict__ resid,
    float* __restrict__ out)
{
    __shared__ u16 lA[2][128 * 32];
    __shared__ u16 lB[2][128 * 32];
    const int tid = threadIdx.x, lane = tid & 63, w = tid >> 6;
    const int l15 = lane & 15, lg = lane >> 4;
    const int wr = w >> 1, wc = w & 1;
    const int m0 = blockIdx.y * 128, n0 = blockIdx.x * 128;

    const u16* aptr[2]; int adst[2];
#pragma unroll
    for (int i = 0; i < 2; ++i) {
        const int rowb = (w * 2 + i) * 16;
        const int row = rowb + (lane >> 2);
        const int gc = (lane & 3) ^ ((row >> 1) & 3);
        aptr[i] = ctx + (size_t)(m0 + row) * DMODEL + gc * 8;
        adst[i] = rowb * 32;
    }
    const int wrow = tid >> 1, wch = tid & 1;
    const float* wp = Wo + (size_t)(n0 + wrow) * DMODEL + wch * 16;
    const int wsw = (wrow >> 1) & 3;
    const int bo0 = wrow * 32 + ((wch * 2) ^ wsw) * 8;
    const int bo1 = wrow * 32 + ((wch * 2 + 1) ^ wsw) * 8;
    int afo[4], bfo[4];
#pragma unroll
    for (int i = 0; i < 4; ++i) {
        const int rA = wr * 64 + i * 16 + l15;
        afo[i] = rA * 32 + ((lg ^ ((rA >> 1) & 3)) * 8);
        const int rB = wc * 64 + i * 16 + l15;
        bfo[i] = rB * 32 + ((lg ^ ((rB >> 1) & 3)) * 8);
    }

    f32x4 acc[4][4] = {};

    load_lds16(aptr[0], &lA[0][adst[0]]);
    load_lds16(aptr[1], &lA[0][adst[1]]);
    {
        const float4 w0 = *(const float4*)(wp);
        const float4 w1 = *(const float4*)(wp + 4);
        const float4 w2 = *(const float4*)(wp + 8);
        const float4 w3 = *(const float4*)(wp + 12);
        *(us8*)&lB[0][bo0] = pack8(w0, w1);
        *(us8*)&lB[0][bo1] = pack8(w2, w3);
    }
    __syncthreads();

    int cur = 0;
    for (int t = 0; t < 32; ++t) {
        float4 w0, w1, w2, w3;
        const bool notlast = (t < 31);
        if (notlast) {
            load_lds16(aptr[0] + (t + 1) * 32, &lA[cur ^ 1][adst[0]]);
            load_lds16(aptr[1] + (t + 1) * 32, &lA[cur ^ 1][adst[1]]);
            w0 = *(const float4*)(wp + (t + 1) * 32);
            w1 = *(const float4*)(wp + (t + 1) * 32 + 4);
            w2 = *(const float4*)(wp + (t + 1) * 32 + 8);
            w3 = *(const float4*)(wp + (t + 1) * 32 + 12);
        }
        bf16x8 af[4], bfr[4];
#pragma unroll
        for (int i = 0; i < 4; ++i) {
            af[i] = *(bf16x8*)&lA[cur][afo[i]];
            bfr[i] = *(bf16x8*)&lB[cur][bfo[i]];
        }
        __builtin_amdgcn_s_setprio(1);
#pragma unroll
        for (int i = 0; i < 4; ++i)
#pragma unroll
            for (int j = 0; j < 4; ++j)
                acc[i][j] = __builtin_amdgcn_mfma_f32_16x16x32_bf16(af[i], bfr[j], acc[i][j], 0, 0, 0);
        __builtin_amdgcn_s_setprio(0);
        if (notlast) {
            *(us8*)&lB[cur ^ 1][bo0] = pack8(w0, w1);
            *(us8*)&lB[cur ^ 1][bo1] = pack8(w2, w3);
            __syncthreads();
            cur ^= 1;
        }
    }

#pragma unroll
    for (int i = 0; i < 4; ++i) {
#pragma unroll
        for (int j = 0; j < 4; ++j) {
            const int n = n0 + wc * 64 + j * 16 + l15;
            const float bnj = bo[n];
#pragma unroll
            for (int e = 0; e < 4; ++e) {
                const int m = m0 + wr * 64 + i * 16 + lg * 4 + e;
                out[(size_t)m * DMODEL + n] = acc[i][j][e] + bnj + resid[(size_t)m * DMODEL + n];
            }
        }
    }
}

// ---------------------------------------------------------------------------
// Flash attention, 8 waves x 16 q-rows (512 threads), KVBLK=128, counted
// vmcnt(8). 80KB LDS, 2 blocks/CU = 16 waves/CU. (r9-proven, kept)
// ---------------------------------------------------------------------------
__global__ __launch_bounds__(512, 4) void attn9(
    const u16* __restrict__ qg, const u16* __restrict__ kg,
    const u16* __restrict__ vTg, const u16* __restrict__ cmb,
    u16* __restrict__ ctx)
{
    __shared__ u16 Kl[2][128 * 64];   // [k-row][dh]  32 KB
    __shared__ u16 Vl[2][64 * 128];   // [dh][k]      32 KB
    __shared__ u16 Pl8[8][16 * 64];   // per-wave P   16 KB

    const int tid = threadIdx.x, lane = tid & 63, w = tid >> 6;  // w 0..7
    const int bx = blockIdx.x;
    const int x = bx & 7, rest = bx >> 3;
    const int qt = rest & 15, g2 = rest >> 4;
    const int hb = g2 * 8 + x;
    const int h = hb & (NH - 1), b = hb >> 4;

    const int l15 = lane & 15, lg = lane >> 4;
    const int q0 = qt * 128 + w * 16;
    const size_t rowbase = (size_t)b * S_LEN * DMODEL + h * DH;
    const size_t vbase = (size_t)(b * NH + h) * DH * S_LEN;
    u16* Pw = Pl8[w];

    bf16x8 aq[2];
#pragma unroll
    for (int kf = 0; kf < 2; ++kf)
        aq[kf] = *(const bf16x8*)&qg[rowbase + (size_t)(q0 + l15) * DMODEL + kf * 32 + lg * 8];

    const int lx = l15 & 7;
    int kbase[2];
#pragma unroll
    for (int kf = 0; kf < 2; ++kf)
        kbase[kf] = l15 * 64 + (((kf * 4 + lg) ^ lx) * 8);
    int vb2[4];
#pragma unroll
    for (int kf2 = 0; kf2 < 4; ++kf2)
        vb2[kf2] = l15 * 128 + (((kf2 * 4 + lg) ^ lx) * 8);
    const int phi = l15 >> 3, plo = l15 & 7;

    size_t ksoff[2], vsoff[2];
    int ldst[2];
#pragma unroll
    for (int t = 0; t < 2; ++t) {
        const int ck = t * 512 + tid;
        const int krow = ck >> 3, kslot = ck & 7;
        ksoff[t] = (size_t)krow * DMODEL + ((kslot ^ (krow & 7)) * 8);
        const int vrow = ck >> 4, vslot = ck & 15;
        vsoff[t] = (size_t)vrow * S_LEN + ((vslot ^ (vrow & 7)) * 8);
        ldst[t] = (t * 512 + w * 64) * 8;
    }
    const u16* cmb_b = cmb + (size_t)b * S_LEN + lg * 8;

    f32x4 po[4] = {};
    f32x4 pol = {};

    bf16x8 cf[4];
#pragma unroll
    for (int j = 0; j < 4; ++j)
        cf[j] = *(const bf16x8*)&cmb_b[j * 32];
    const u16* kp = kg + rowbase;
    const u16* vp = vTg + vbase;
#pragma unroll
    for (int t = 0; t < 2; ++t) {
        load_lds16(kp + ksoff[t], &Kl[0][ldst[t]]);
        load_lds16(vp + vsoff[t], &Vl[0][ldst[t]]);
    }
    kp += 128 * DMODEL; vp += 128;

    int cur = 0;
    for (int kt = 0; kt < S_LEN / 128; ++kt) {
        bf16x8 nx[4];
        if (kt + 1 < S_LEN / 128) {
#pragma unroll
            for (int j = 0; j < 4; ++j)
                nx[j] = *(const bf16x8*)&cmb_b[(kt + 1) * 128 + j * 32];
#pragma unroll
            for (int t = 0; t < 2; ++t) {
                load_lds16(kp + ksoff[t], &Kl[cur ^ 1][ldst[t]]);
                load_lds16(vp + vsoff[t], &Vl[cur ^ 1][ldst[t]]);
            }
            kp += 128 * DMODEL; vp += 128;
            asm volatile("s_waitcnt vmcnt(8)" ::: "memory");
        } else {
#pragma unroll
            for (int j = 0; j < 4; ++j) nx[j] = cf[j];
            asm volatile("s_waitcnt vmcnt(0)" ::: "memory");
        }
        __builtin_amdgcn_s_barrier();
        __builtin_amdgcn_sched_barrier(0);

#pragma unroll
        for (int h2 = 0; h2 < 2; ++h2) {
            f32x4 sa[4] = {};
            bf16x8 bkf[4][2];
#pragma unroll
            for (int nf = 0; nf < 4; ++nf)
#pragma unroll
                for (int kf = 0; kf < 2; ++kf)
                    bkf[nf][kf] = *(bf16x8*)&Kl[cur][(h2 * 4 + nf) * 1024 + kbase[kf]];
            __builtin_amdgcn_s_setprio(1);
#pragma unroll
            for (int nf = 0; nf < 4; ++nf)
#pragma unroll
                for (int kf = 0; kf < 2; ++kf)
                    sa[nf] = __builtin_amdgcn_mfma_f32_16x16x32_bf16(aq[kf], bkf[nf][kf], sa[nf], 0, 0, 0);
            __builtin_amdgcn_s_setprio(0);

#pragma unroll
            for (int e = 0; e < 4; ++e) {
                const int prow = lg * 4 + e;
                const int pbase = prow * 64 + plo;
                const int pxor = prow & 7;
#pragma unroll
                for (int nf = 0; nf < 4; ++nf) {
                    union { float f; unsigned u; } cv;
                    cv.f = exp2f(sa[nf][e]);
                    Pw[pbase + (((nf * 2 + phi) ^ pxor) * 8)] = (u16)(cv.u >> 16);
                }
            }

#pragma unroll
            for (int j = 0; j < 2; ++j) {
                const int kf2 = h2 * 2 + j;
                bf16x8 ap = *(bf16x8*)&Pw[kbase[j]];
                bf16x8 bv[4];
#pragma unroll
                for (int df = 0; df < 4; ++df)
                    bv[df] = *(bf16x8*)&Vl[cur][df * 2048 + vb2[kf2]];
                const bf16x8 cfk = cf[kf2];
                __builtin_amdgcn_s_setprio(1);
#pragma unroll
                for (int df = 0; df < 4; ++df)
                    po[df] = __builtin_amdgcn_mfma_f32_16x16x32_bf16(ap, bv[df], po[df], 0, 0, 0);
                pol = __builtin_amdgcn_mfma_f32_16x16x32_bf16(ap, cfk, pol, 0, 0, 0);
                __builtin_amdgcn_s_setprio(0);
            }
        }
        __builtin_amdgcn_s_barrier();
#pragma unroll
        for (int j = 0; j < 4; ++j) cf[j] = nx[j];
        cur ^= 1;
    }

#pragma unroll
    for (int e = 0; e < 4; ++e) {
        const float inv = 1.0f / pol[e];
        const int qrow = q0 + lg * 4 + e;
#pragma unroll
        for (int df = 0; df < 4; ++df)
            ctx[((size_t)b * S_LEN + qrow) * DMODEL + h * DH + df * 16 + l15] = f2bf(po[df][e] * inv);
    }
}

// ---------------------------------------------------------------------------
// LayerNorm in-place, one row per block
// ---------------------------------------------------------------------------
__global__ __launch_bounds__(256) void ln_kernel(
    float* __restrict__ x, const float* __restrict__ gamma, const float* __restrict__ beta)
{
    const int row = blockIdx.x;
    const int tid = threadIdx.x;
    float4 vv = *(float4*)(x + (size_t)row * DMODEL + tid * 4);
    float s = vv.x + vv.y + vv.z + vv.w;
    float s2 = vv.x * vv.x + vv.y * vv.y + vv.z * vv.z + vv.w * vv.w;
#pragma unroll
    for (int d = 1; d < 64; d <<= 1) { s += __shfl_xor(s, d); s2 += __shfl_xor(s2, d); }
    __shared__ float rs[4], rs2[4];
    if ((tid & 63) == 0) { rs[tid >> 6] = s; rs2[tid >> 6] = s2; }
    __syncthreads();
    s = rs[0] + rs[1] + rs[2] + rs[3];
    s2 = rs2[0] + rs2[1] + rs2[2] + rs2[3];
    const float mu = s * (1.f / DMODEL);
    const float var = s2 * (1.f / DMODEL) - mu * mu;
    const float inv = rsqrtf(var + 1e-5f);
    const float4 g = *(const float4*)(gamma + tid * 4);
    const float4 bt = *(const float4*)(beta + tid * 4);
    vv.x = (vv.x - mu) * inv * g.x + bt.x;
    vv.y = (vv.y - mu) * inv * g.y + bt.y;
    vv.z = (vv.z - mu) * inv * g.z + bt.z;
    vv.w = (vv.w - mu) * inv * g.w + bt.w;
    *(float4*)(x + (size_t)row * DMODEL + tid * 4) = vv;
}

extern "C" void kernel_launch(void* const* d_in, const int* in_sizes, int n_in,
                              void* d_out, int out_size, void* d_ws, size_t ws_size,
                              hipStream_t stream) {
    const float* hs    = (const float*)d_in[0];
    const float* mask  = (const float*)d_in[1];
    const float* Wq    = (const float*)d_in[2];
    const float* bq    = (const float*)d_in[3];
    const float* Wk    = (const float*)d_in[4];
    const float* bk    = (const float*)d_in[5];
    const float* Wv    = (const float*)d_in[6];
    const float* bv    = (const float*)d_in[7];
    const float* Wo    = (const float*)d_in[9];
    const float* bo    = (const float*)d_in[10];
    const float* gamma = (const float*)d_in[11];
    const float* beta  = (const float*)d_in[12];
    float* out = (float*)d_out;

    const size_t MN = (size_t)M_TOT * DMODEL;     // 4M elements
    u16* qb      = (u16*)d_ws;          // [0, 8MB)
    u16* kb      = qb + MN;             // [8, 16MB)
    u16* vT      = kb + MN;             // [16, 24MB)
    u16* scratch = vT + MN;             // [24, 32MB): hsb, then ctx

    float* cm = out + MN - 4096 - 2048;
    u16*  cmb = (u16*)(out + MN - 2048);

    dim3 blk(256);

    conv_bf16<<<MN / 2048, blk, 0, stream>>>(hs, scratch);
    gen_cm<<<(2 * S_LEN) / 256, blk, 0, stream>>>(mask, cm, cmb);
    gemm_qkv<<<dim3(DMODEL / 128, M_TOT / 128, 3), blk, 0, stream>>>(
        scratch, Wq, Wk, Wv, bq, bk, bv, cm, qb, kb, vT);
    attn9<<<dim3(512), dim3(512), 0, stream>>>(qb, kb, vT, cmb, scratch);
    gemm_o<<<dim3(DMODEL / 128, M_TOT / 128), blk, 0, stream>>>(scratch, Wo, bo, hs, out);
    ln_kernel<<<M_TOT, blk, 0, stream>>>(out, gamma, beta);
}

// Round 11
// 152.924 us; speedup vs baseline: 1.2244x; 1.1029x over previous
//
#include <hip/hip_runtime.h>
#include <hip/hip_bf16.h>

#define S_LEN 2048
#define NH 16
#define DH 64
#define DMODEL 1024
#define M_TOT 4096
#define LOG2E 1.44269504f

typedef __attribute__((ext_vector_type(8))) short bf16x8;
typedef __attribute__((ext_vector_type(4))) float f32x4;
typedef unsigned short u16;
typedef unsigned short us8 __attribute__((ext_vector_type(8)));

__device__ inline u16 f2bf(float f) {
    union { float f; unsigned u; } c; c.f = f;
    unsigned r = c.u + 0x7fffu + ((c.u >> 16) & 1u);
    return (u16)(r >> 16);
}

__device__ inline void load_lds16(const u16* g, u16* l) {
    __builtin_amdgcn_global_load_lds((const __attribute__((address_space(1))) void*)g,
                                     (__attribute__((address_space(3))) void*)l, 16, 0, 0);
}

__device__ inline us8 pack8(float4 a, float4 b) {
    us8 o;
    o[0] = f2bf(a.x); o[1] = f2bf(a.y); o[2] = f2bf(a.z); o[3] = f2bf(a.w);
    o[4] = f2bf(b.x); o[5] = f2bf(b.y); o[6] = f2bf(b.z); o[7] = f2bf(b.w);
    return o;
}

// ---------------------------------------------------------------------------
// fp32 -> bf16 (RNE), grid*2048 elements
// ---------------------------------------------------------------------------
__global__ __launch_bounds__(256) void conv_bf16(
    const float* __restrict__ src, u16* __restrict__ dst)
{
    const size_t i = ((size_t)blockIdx.x * 256 + threadIdx.x) * 8;
    const float4 a = *(const float4*)(src + i);
    const float4 b = *(const float4*)(src + i + 4);
    *(us8*)(dst + i) = pack8(a, b);
}

// ---------------------------------------------------------------------------
// Convert Wq,Wk,Wv,Wo fp32 -> bf16 contiguous at dst (z selects weight)
// ---------------------------------------------------------------------------
__global__ __launch_bounds__(256) void conv4(
    const float* __restrict__ w0, const float* __restrict__ w1,
    const float* __restrict__ w2, const float* __restrict__ w3,
    u16* __restrict__ dst)
{
    const int z = blockIdx.y;
    const float* src = (z == 0) ? w0 : (z == 1) ? w1 : (z == 2) ? w2 : w3;
    const size_t i = ((size_t)blockIdx.x * 256 + threadIdx.x) * 8;
    const float4 a = *(const float4*)(src + i);
    const float4 b = *(const float4*)(src + i + 4);
    *(us8*)(dst + (size_t)z * (DMODEL * DMODEL) + i) = pack8(a, b);
}

// ---------------------------------------------------------------------------
// cm[b,s] = e^{mask[b,s]} (f32 + bf16). B*S = 4096 elements.
// ---------------------------------------------------------------------------
__global__ __launch_bounds__(256) void gen_cm(
    const float* __restrict__ mask, float* __restrict__ cm, u16* __restrict__ cmb)
{
    const int i = blockIdx.x * 256 + threadIdx.x;
    const float c = exp2f(mask[i] * LOG2E);
    cm[i] = c;
    cmb[i] = f2bf(c);
}

// ---------------------------------------------------------------------------
// QKV GEMM: BOTH operands bf16 via global_load_lds, counted vmcnt(4) pipeline.
// z=0: Q flat scaled by 0.125*log2e; z=1: K flat; z=2: V*cm -> vT (B,H,DH,S)
// ---------------------------------------------------------------------------
__global__ __launch_bounds__(256) void gemm_qkv(
    const u16* __restrict__ hsb, const u16* __restrict__ wbf,
    const float* __restrict__ bq, const float* __restrict__ bk, const float* __restrict__ bv,
    const float* __restrict__ cm,
    u16* __restrict__ qb, u16* __restrict__ kb, u16* __restrict__ vT)
{
    __shared__ u16 lA[2][128 * 32];
    __shared__ u16 lB[2][128 * 32];
    const int tid = threadIdx.x, lane = tid & 63, w = tid >> 6;
    const int l15 = lane & 15, lg = lane >> 4;
    const int wr = w >> 1, wc = w & 1;
    const int m0 = blockIdx.y * 128, n0 = blockIdx.x * 128;
    const int z = blockIdx.z;
    const u16* Wp = wbf + (size_t)z * (DMODEL * DMODEL);
    const float* bias = (z == 0) ? bq : (z == 1) ? bk : bv;

    const u16 *aptr[2], *wptr[2]; int adst[2];
#pragma unroll
    for (int i = 0; i < 2; ++i) {
        const int rowb = (w * 2 + i) * 16;
        const int row = rowb + (lane >> 2);
        const int gc = (lane & 3) ^ ((row >> 1) & 3);
        aptr[i] = hsb + (size_t)(m0 + row) * DMODEL + gc * 8;
        wptr[i] = Wp + (size_t)(n0 + row) * DMODEL + gc * 8;
        adst[i] = rowb * 32;
    }
    int afo[4], bfo[4];
#pragma unroll
    for (int i = 0; i < 4; ++i) {
        const int rA = wr * 64 + i * 16 + l15;
        afo[i] = rA * 32 + ((lg ^ ((rA >> 1) & 3)) * 8);
        const int rB = wc * 64 + i * 16 + l15;
        bfo[i] = rB * 32 + ((lg ^ ((rB >> 1) & 3)) * 8);
    }

    f32x4 acc[4][4] = {};

    // prologue: DMA tile 0 (4 per wave)
#pragma unroll
    for (int i = 0; i < 2; ++i) {
        load_lds16(aptr[i], &lA[0][adst[i]]);
        load_lds16(wptr[i], &lB[0][adst[i]]);
    }

    int cur = 0;
    for (int t = 0; t < 32; ++t) {
        if (t < 31) {
#pragma unroll
            for (int i = 0; i < 2; ++i) {
                load_lds16(aptr[i] + (t + 1) * 32, &lA[cur ^ 1][adst[i]]);
                load_lds16(wptr[i] + (t + 1) * 32, &lB[cur ^ 1][adst[i]]);
            }
            asm volatile("s_waitcnt vmcnt(4)" ::: "memory");
        } else {
            asm volatile("s_waitcnt vmcnt(0)" ::: "memory");
        }
        __builtin_amdgcn_s_barrier();
        __builtin_amdgcn_sched_barrier(0);

        bf16x8 af[4], bfr[4];
#pragma unroll
        for (int i = 0; i < 4; ++i) {
            af[i] = *(bf16x8*)&lA[cur][afo[i]];
            bfr[i] = *(bf16x8*)&lB[cur][bfo[i]];
        }
        __builtin_amdgcn_s_setprio(1);
#pragma unroll
        for (int i = 0; i < 4; ++i)
#pragma unroll
            for (int j = 0; j < 4; ++j)
                acc[i][j] = __builtin_amdgcn_mfma_f32_16x16x32_bf16(af[i], bfr[j], acc[i][j], 0, 0, 0);
        __builtin_amdgcn_s_setprio(0);
        __builtin_amdgcn_s_barrier();
        cur ^= 1;
    }

    const float qsc = 0.125f * LOG2E;
    float bn[4];
#pragma unroll
    for (int j = 0; j < 4; ++j) bn[j] = bias[n0 + wc * 64 + j * 16 + l15];

#pragma unroll
    for (int i = 0; i < 4; ++i) {
        const int mbase = m0 + wr * 64 + i * 16 + lg * 4;
        if (z == 0) {
#pragma unroll
            for (int j = 0; j < 4; ++j) {
                const int n = n0 + wc * 64 + j * 16 + l15;
#pragma unroll
                for (int e = 0; e < 4; ++e)
                    qb[(size_t)(mbase + e) * DMODEL + n] = f2bf((acc[i][j][e] + bn[j]) * qsc);
            }
        } else if (z == 1) {
#pragma unroll
            for (int j = 0; j < 4; ++j) {
                const int n = n0 + wc * 64 + j * 16 + l15;
#pragma unroll
                for (int e = 0; e < 4; ++e)
                    kb[(size_t)(mbase + e) * DMODEL + n] = f2bf(acc[i][j][e] + bn[j]);
            }
        } else {
            const int bb = mbase >> 11, s = mbase & 2047;
            const float4 c4 = *(const float4*)&cm[bb * S_LEN + s];
#pragma unroll
            for (int j = 0; j < 4; ++j) {
                const int n = n0 + wc * 64 + j * 16 + l15;
                const int hh = n >> 6, dh = n & 63;
                ushort4 uv;
                uv.x = f2bf((acc[i][j][0] + bn[j]) * c4.x);
                uv.y = f2bf((acc[i][j][1] + bn[j]) * c4.y);
                uv.z = f2bf((acc[i][j][2] + bn[j]) * c4.z);
                uv.w = f2bf((acc[i][j][3] + bn[j]) * c4.w);
                *(ushort4*)&vT[((size_t)(bb * NH + hh) * DH + dh) * S_LEN + s] = uv;
            }
        }
    }
}

// ---------------------------------------------------------------------------
// O-projection: both operands bf16 via DMA, counted vmcnt(4); writes X (fp32)
// to workspace (LN reads X and writes d_out).
// ---------------------------------------------------------------------------
__global__ __launch_bounds__(256) void gemm_o(
    const u16* __restrict__ ctx, const u16* __restrict__ wobf,
    const float* __restrict__ bo, const float* __restrict__ resid,
    float* __restrict__ X)
{
    __shared__ u16 lA[2][128 * 32];
    __shared__ u16 lB[2][128 * 32];
    const int tid = threadIdx.x, lane = tid & 63, w = tid >> 6;
    const int l15 = lane & 15, lg = lane >> 4;
    const int wr = w >> 1, wc = w & 1;
    const int m0 = blockIdx.y * 128, n0 = blockIdx.x * 128;

    const u16 *aptr[2], *wptr[2]; int adst[2];
#pragma unroll
    for (int i = 0; i < 2; ++i) {
        const int rowb = (w * 2 + i) * 16;
        const int row = rowb + (lane >> 2);
        const int gc = (lane & 3) ^ ((row >> 1) & 3);
        aptr[i] = ctx + (size_t)(m0 + row) * DMODEL + gc * 8;
        wptr[i] = wobf + (size_t)(n0 + row) * DMODEL + gc * 8;
        adst[i] = rowb * 32;
    }
    int afo[4], bfo[4];
#pragma unroll
    for (int i = 0; i < 4; ++i) {
        const int rA = wr * 64 + i * 16 + l15;
        afo[i] = rA * 32 + ((lg ^ ((rA >> 1) & 3)) * 8);
        const int rB = wc * 64 + i * 16 + l15;
        bfo[i] = rB * 32 + ((lg ^ ((rB >> 1) & 3)) * 8);
    }

    f32x4 acc[4][4] = {};

#pragma unroll
    for (int i = 0; i < 2; ++i) {
        load_lds16(aptr[i], &lA[0][adst[i]]);
        load_lds16(wptr[i], &lB[0][adst[i]]);
    }

    int cur = 0;
    for (int t = 0; t < 32; ++t) {
        if (t < 31) {
#pragma unroll
            for (int i = 0; i < 2; ++i) {
                load_lds16(aptr[i] + (t + 1) * 32, &lA[cur ^ 1][adst[i]]);
                load_lds16(wptr[i] + (t + 1) * 32, &lB[cur ^ 1][adst[i]]);
            }
            asm volatile("s_waitcnt vmcnt(4)" ::: "memory");
        } else {
            asm volatile("s_waitcnt vmcnt(0)" ::: "memory");
        }
        __builtin_amdgcn_s_barrier();
        __builtin_amdgcn_sched_barrier(0);

        bf16x8 af[4], bfr[4];
#pragma unroll
        for (int i = 0; i < 4; ++i) {
            af[i] = *(bf16x8*)&lA[cur][afo[i]];
            bfr[i] = *(bf16x8*)&lB[cur][bfo[i]];
        }
        __builtin_amdgcn_s_setprio(1);
#pragma unroll
        for (int i = 0; i < 4; ++i)
#pragma unroll
            for (int j = 0; j < 4; ++j)
                acc[i][j] = __builtin_amdgcn_mfma_f32_16x16x32_bf16(af[i], bfr[j], acc[i][j], 0, 0, 0);
        __builtin_amdgcn_s_setprio(0);
        __builtin_amdgcn_s_barrier();
        cur ^= 1;
    }

#pragma unroll
    for (int i = 0; i < 4; ++i) {
#pragma unroll
        for (int j = 0; j < 4; ++j) {
            const int n = n0 + wc * 64 + j * 16 + l15;
            const float bnj = bo[n];
#pragma unroll
            for (int e = 0; e < 4; ++e) {
                const int m = m0 + wr * 64 + i * 16 + lg * 4 + e;
                X[(size_t)m * DMODEL + n] = acc[i][j][e] + bnj + resid[(size_t)m * DMODEL + n];
            }
        }
    }
}

// ---------------------------------------------------------------------------
// Flash attention, 8 waves x 16 q-rows (512 threads), KVBLK=128, counted
// vmcnt(8). 80KB LDS, 2 blocks/CU = 16 waves/CU. (r10-proven, verbatim)
// ---------------------------------------------------------------------------
__global__ __launch_bounds__(512, 4) void attn9(
    const u16* __restrict__ qg, const u16* __restrict__ kg,
    const u16* __restrict__ vTg, const u16* __restrict__ cmb,
    u16* __restrict__ ctx)
{
    __shared__ u16 Kl[2][128 * 64];
    __shared__ u16 Vl[2][64 * 128];
    __shared__ u16 Pl8[8][16 * 64];

    const int tid = threadIdx.x, lane = tid & 63, w = tid >> 6;
    const int bx = blockIdx.x;
    const int x = bx & 7, rest = bx >> 3;
    const int qt = rest & 15, g2 = rest >> 4;
    const int hb = g2 * 8 + x;
    const int h = hb & (NH - 1), b = hb >> 4;

    const int l15 = lane & 15, lg = lane >> 4;
    const int q0 = qt * 128 + w * 16;
    const size_t rowbase = (size_t)b * S_LEN * DMODEL + h * DH;
    const size_t vbase = (size_t)(b * NH + h) * DH * S_LEN;
    u16* Pw = Pl8[w];

    bf16x8 aq[2];
#pragma unroll
    for (int kf = 0; kf < 2; ++kf)
        aq[kf] = *(const bf16x8*)&qg[rowbase + (size_t)(q0 + l15) * DMODEL + kf * 32 + lg * 8];

    const int lx = l15 & 7;
    int kbase[2];
#pragma unroll
    for (int kf = 0; kf < 2; ++kf)
        kbase[kf] = l15 * 64 + (((kf * 4 + lg) ^ lx) * 8);
    int vb2[4];
#pragma unroll
    for (int kf2 = 0; kf2 < 4; ++kf2)
        vb2[kf2] = l15 * 128 + (((kf2 * 4 + lg) ^ lx) * 8);
    const int phi = l15 >> 3, plo = l15 & 7;

    size_t ksoff[2], vsoff[2];
    int ldst[2];
#pragma unroll
    for (int t = 0; t < 2; ++t) {
        const int ck = t * 512 + tid;
        const int krow = ck >> 3, kslot = ck & 7;
        ksoff[t] = (size_t)krow * DMODEL + ((kslot ^ (krow & 7)) * 8);
        const int vrow = ck >> 4, vslot = ck & 15;
        vsoff[t] = (size_t)vrow * S_LEN + ((vslot ^ (vrow & 7)) * 8);
        ldst[t] = (t * 512 + w * 64) * 8;
    }
    const u16* cmb_b = cmb + (size_t)b * S_LEN + lg * 8;

    f32x4 po[4] = {};
    f32x4 pol = {};

    bf16x8 cf[4];
#pragma unroll
    for (int j = 0; j < 4; ++j)
        cf[j] = *(const bf16x8*)&cmb_b[j * 32];
    const u16* kp = kg + rowbase;
    const u16* vp = vTg + vbase;
#pragma unroll
    for (int t = 0; t < 2; ++t) {
        load_lds16(kp + ksoff[t], &Kl[0][ldst[t]]);
        load_lds16(vp + vsoff[t], &Vl[0][ldst[t]]);
    }
    kp += 128 * DMODEL; vp += 128;

    int cur = 0;
    for (int kt = 0; kt < S_LEN / 128; ++kt) {
        bf16x8 nx[4];
        if (kt + 1 < S_LEN / 128) {
#pragma unroll
            for (int j = 0; j < 4; ++j)
                nx[j] = *(const bf16x8*)&cmb_b[(kt + 1) * 128 + j * 32];
#pragma unroll
            for (int t = 0; t < 2; ++t) {
                load_lds16(kp + ksoff[t], &Kl[cur ^ 1][ldst[t]]);
                load_lds16(vp + vsoff[t], &Vl[cur ^ 1][ldst[t]]);
            }
            kp += 128 * DMODEL; vp += 128;
            asm volatile("s_waitcnt vmcnt(8)" ::: "memory");
        } else {
#pragma unroll
            for (int j = 0; j < 4; ++j) nx[j] = cf[j];
            asm volatile("s_waitcnt vmcnt(0)" ::: "memory");
        }
        __builtin_amdgcn_s_barrier();
        __builtin_amdgcn_sched_barrier(0);

#pragma unroll
        for (int h2 = 0; h2 < 2; ++h2) {
            f32x4 sa[4] = {};
            bf16x8 bkf[4][2];
#pragma unroll
            for (int nf = 0; nf < 4; ++nf)
#pragma unroll
                for (int kf = 0; kf < 2; ++kf)
                    bkf[nf][kf] = *(bf16x8*)&Kl[cur][(h2 * 4 + nf) * 1024 + kbase[kf]];
            __builtin_amdgcn_s_setprio(1);
#pragma unroll
            for (int nf = 0; nf < 4; ++nf)
#pragma unroll
                for (int kf = 0; kf < 2; ++kf)
                    sa[nf] = __builtin_amdgcn_mfma_f32_16x16x32_bf16(aq[kf], bkf[nf][kf], sa[nf], 0, 0, 0);
            __builtin_amdgcn_s_setprio(0);

#pragma unroll
            for (int e = 0; e < 4; ++e) {
                const int prow = lg * 4 + e;
                const int pbase = prow * 64 + plo;
                const int pxor = prow & 7;
#pragma unroll
                for (int nf = 0; nf < 4; ++nf) {
                    union { float f; unsigned u; } cv;
                    cv.f = exp2f(sa[nf][e]);
                    Pw[pbase + (((nf * 2 + phi) ^ pxor) * 8)] = (u16)(cv.u >> 16);
                }
            }

#pragma unroll
            for (int j = 0; j < 2; ++j) {
                const int kf2 = h2 * 2 + j;
                bf16x8 ap = *(bf16x8*)&Pw[kbase[j]];
                bf16x8 bv[4];
#pragma unroll
                for (int df = 0; df < 4; ++df)
                    bv[df] = *(bf16x8*)&Vl[cur][df * 2048 + vb2[kf2]];
                const bf16x8 cfk = cf[kf2];
                __builtin_amdgcn_s_setprio(1);
#pragma unroll
                for (int df = 0; df < 4; ++df)
                    po[df] = __builtin_amdgcn_mfma_f32_16x16x32_bf16(ap, bv[df], po[df], 0, 0, 0);
                pol = __builtin_amdgcn_mfma_f32_16x16x32_bf16(ap, cfk, pol, 0, 0, 0);
                __builtin_amdgcn_s_setprio(0);
            }
        }
        __builtin_amdgcn_s_barrier();
#pragma unroll
        for (int j = 0; j < 4; ++j) cf[j] = nx[j];
        cur ^= 1;
    }

#pragma unroll
    for (int e = 0; e < 4; ++e) {
        const float inv = 1.0f / pol[e];
        const int qrow = q0 + lg * 4 + e;
#pragma unroll
        for (int df = 0; df < 4; ++df)
            ctx[((size_t)b * S_LEN + qrow) * DMODEL + h * DH + df * 16 + l15] = f2bf(po[df][e] * inv);
    }
}

// ---------------------------------------------------------------------------
// LayerNorm: reads X (ws), writes d_out
// ---------------------------------------------------------------------------
__global__ __launch_bounds__(256) void ln_kernel(
    const float* __restrict__ xin, float* __restrict__ y,
    const float* __restrict__ gamma, const float* __restrict__ beta)
{
    const int row = blockIdx.x;
    const int tid = threadIdx.x;
    float4 vv = *(const float4*)(xin + (size_t)row * DMODEL + tid * 4);
    float s = vv.x + vv.y + vv.z + vv.w;
    float s2 = vv.x * vv.x + vv.y * vv.y + vv.z * vv.z + vv.w * vv.w;
#pragma unroll
    for (int d = 1; d < 64; d <<= 1) { s += __shfl_xor(s, d); s2 += __shfl_xor(s2, d); }
    __shared__ float rs[4], rs2[4];
    if ((tid & 63) == 0) { rs[tid >> 6] = s; rs2[tid >> 6] = s2; }
    __syncthreads();
    s = rs[0] + rs[1] + rs[2] + rs[3];
    s2 = rs2[0] + rs2[1] + rs2[2] + rs2[3];
    const float mu = s * (1.f / DMODEL);
    const float var = s2 * (1.f / DMODEL) - mu * mu;
    const float inv = rsqrtf(var + 1e-5f);
    const float4 g = *(const float4*)(gamma + tid * 4);
    const float4 bt = *(const float4*)(beta + tid * 4);
    vv.x = (vv.x - mu) * inv * g.x + bt.x;
    vv.y = (vv.y - mu) * inv * g.y + bt.y;
    vv.z = (vv.z - mu) * inv * g.z + bt.z;
    vv.w = (vv.w - mu) * inv * g.w + bt.w;
    *(float4*)(y + (size_t)row * DMODEL + tid * 4) = vv;
}

extern "C" void kernel_launch(void* const* d_in, const int* in_sizes, int n_in,
                              void* d_out, int out_size, void* d_ws, size_t ws_size,
                              hipStream_t stream) {
    const float* hs    = (const float*)d_in[0];
    const float* mask  = (const float*)d_in[1];
    const float* Wq    = (const float*)d_in[2];
    const float* bq    = (const float*)d_in[3];
    const float* Wk    = (const float*)d_in[4];
    const float* bk    = (const float*)d_in[5];
    const float* Wv    = (const float*)d_in[6];
    const float* bv    = (const float*)d_in[7];
    const float* Wo    = (const float*)d_in[9];
    const float* bo    = (const float*)d_in[10];
    const float* gamma = (const float*)d_in[11];
    const float* beta  = (const float*)d_in[12];
    float* out = (float*)d_out;

    const size_t MN = (size_t)M_TOT * DMODEL;     // 4M elements
    const size_t WN = (size_t)DMODEL * DMODEL;    // 1M elements
    // d_ws (32 MB): qb[0,8) kb[8,16) vT[16,24) scratch[24,32): hsb then ctx
    u16* qb      = (u16*)d_ws;
    u16* kb      = qb + MN;
    u16* vT      = kb + MN;
    u16* scratch = vT + MN;
    float* X     = (float*)d_ws;        // 16 MB over qb+kb (dead after attn)

    // d_out (16 MB): wbf (4 weights bf16, 8 MB) at front; cm/cmb at tail.
    // All dead before ln_kernel writes d_out.
    u16*  wbf = (u16*)out;
    float* cm = out + MN - 4096 - 2048;
    u16*  cmb = (u16*)(out + MN - 2048);

    dim3 blk(256);

    conv_bf16<<<MN / 2048, blk, 0, stream>>>(hs, scratch);              // hs -> hsb
    conv4<<<dim3(WN / 2048, 4), blk, 0, stream>>>(Wq, Wk, Wv, Wo, wbf); // weights -> bf16
    gen_cm<<<(2 * S_LEN) / 256, blk, 0, stream>>>(mask, cm, cmb);
    gemm_qkv<<<dim3(DMODEL / 128, M_TOT / 128, 3), blk, 0, stream>>>(
        scratch, wbf, bq, bk, bv, cm, qb, kb, vT);
    attn9<<<dim3(512), dim3(512), 0, stream>>>(qb, kb, vT, cmb, scratch); // ctx over hsb
    gemm_o<<<dim3(DMODEL / 128, M_TOT / 128), blk, 0, stream>>>(
        scratch, wbf + 3 * WN, bo, hs, X);                               // X over qb/kb
    ln_kernel<<<M_TOT, blk, 0, stream>>>(X, out, gamma, beta);
}